// Round 20
// baseline (61.731 us; speedup 1.0000x reference)
//
#include <hip/hip_runtime.h>
#include <hip/hip_fp16.h>
#include <math.h>

#define NE 16
#define HD 1024
#define FD 2048

typedef _Float16 half8 __attribute__((ext_vector_type(8)));
typedef float f32x4 __attribute__((ext_vector_type(4)));

// ws layout (4-byte units) — ws is ~512 MB, plenty.
#define TOPI_OFF 0          // 256 int
#define TOPW_OFF 256        // 256 float
#define CNT_OFF  512        // 16 int
#define PREF_OFF 528        // 16 int
#define SLOT_OFF 544        // 256 int (pair -> slot)
#define INVT_OFF 800        // 256 int (slot -> token)
#define META_OFF 1056       // 1 int: M1
#define TL1_OFF  1060       // 64 int  (e<<8|mt) 16-token tiles
#define WSL_OFF  1124       // 256 float (slot -> routing weight)
#define HBUF_OFF 4096                   // h  fp16 [256][2048] = 262144 ints

union XI { int4 v; half8 h; };

// raw workgroup barrier: LDS writes visible (lgkmcnt 0) but vector loads stay
// in flight (no vmcnt drain — the __syncthreads() drain is what caps prefetch depth)
#define BARRIER_LDS() asm volatile("s_waitcnt lgkmcnt(0)\ns_barrier" ::: "memory")

// fp4 e2m1 nibble -> fp16 bits (unscaled)
__device__ __forceinline__ int fp4h(int nib) {
    int c = nib & 7;
    int v;
    if (c == 0) v = 0;
    else if (c == 1) v = 14 << 10;                        // 0.5
    else v = (((c >> 1) + 14) << 10) | ((c & 1) << 9);
    v |= (nib & 8) << 12;
    return v;
}

// LUT byte -> 2 packed fp16 times packed pow2 scale (exact)
__device__ __forceinline__ int dec2i(const int* lut, int byte, int sv) {
    int l = lut[byte & 255];
    __half2 p = *reinterpret_cast<const __half2*>(&l);
    __half2 sc = *reinterpret_cast<const __half2*>(&sv);
    __half2 r = __hmul2(p, sc);
    return *reinterpret_cast<int*>(&r);
}

// decode 8 bytes (2 int4 of weights) + write swizzled to B tile
__device__ __forceinline__ void stageB(const int* lut, int4* Bbuf, int rs, int kq,
                                       int4 q0, int4 q1, int sc) {
    int sv = (sc - 112) << 10; sv |= sv << 16;
    int4 o0, o1;
    o0.x = dec2i(lut, q0.x, sv); o0.y = dec2i(lut, q0.y, sv);
    o0.z = dec2i(lut, q0.z, sv); o0.w = dec2i(lut, q0.w, sv);
    o1.x = dec2i(lut, q1.x, sv); o1.y = dec2i(lut, q1.y, sv);
    o1.z = dec2i(lut, q1.z, sv); o1.w = dec2i(lut, q1.w, sv);
    Bbuf[rs * 8 + ((kq * 2) ^ (rs & 7))] = o0;
    Bbuf[rs * 8 + ((kq * 2 + 1) ^ (rs & 7))] = o1;
}

// f32x4 -> 4 fp16 -> int2 write into A tile
__device__ __forceinline__ void stageA1(int4* Abuf, int a2idx, int4 av) {
    union { int4 v; float f[4]; } uf; uf.v = av;
    union { _Float16 h[4]; int2 p; } o;
    o.h[0] = (_Float16)uf.f[0]; o.h[1] = (_Float16)uf.f[1];
    o.h[2] = (_Float16)uf.f[2]; o.h[3] = (_Float16)uf.f[3];
    ((int2*)Abuf)[a2idx] = o.p;
}

__global__ void routing_kernel(const float* __restrict__ x, const float* __restrict__ rw,
                               int* __restrict__ top_idx, float* __restrict__ top_w) {
    int t = blockIdx.x;
    int tid = threadIdx.x;          // 256
    int e = tid >> 4, seg = tid & 15;
    const float4* xr = (const float4*)(x + t * HD + seg * 64);
    const float4* wr = (const float4*)(rw + e * HD + seg * 64);
    float p = 0.f;
    #pragma unroll
    for (int i = 0; i < 16; ++i) {
        float4 a = xr[i], b = wr[i];
        p = fmaf(a.x, b.x, fmaf(a.y, b.y, fmaf(a.z, b.z, fmaf(a.w, b.w, p))));
    }
    __shared__ float part[16][16];
    __shared__ float logit[16];
    part[e][seg] = p;
    __syncthreads();
    if (tid < 16) {
        float s = 0.f;
        #pragma unroll
        for (int i = 0; i < 16; ++i) s += part[tid][i];
        logit[tid] = s;
    }
    __syncthreads();
    if (tid == 0) {
        int i0 = 0; float v0 = logit[0];
        #pragma unroll
        for (int i = 1; i < 16; ++i) { if (logit[i] > v0) { v0 = logit[i]; i0 = i; } }
        int i1 = -1; float v1 = -1e30f;
        #pragma unroll
        for (int i = 0; i < 16; ++i) { if (i != i0 && logit[i] > v1) { v1 = logit[i]; i1 = i; } }
        float w0 = 1.f / (1.f + expf(v1 - v0));
        float w1 = 1.f / (1.f + expf(v0 - v1));
        top_idx[t * 2]     = i0;  top_w[t * 2]     = w0;
        top_idx[t * 2 + 1] = i1;  top_w[t * 2 + 1] = w1;
    }
}

__global__ void build_kernel(const int* __restrict__ top_idx, const float* __restrict__ top_w,
                             int* __restrict__ cnt, int* __restrict__ pref,
                             int* __restrict__ slot, int* __restrict__ invtok,
                             float* __restrict__ wslot,
                             int* __restrict__ meta, int* __restrict__ tl1) {
    __shared__ int scnt[16], spref[16], scur[16];
    int tid = threadIdx.x;          // 256
    if (tid < 16) scnt[tid] = 0;
    __syncthreads();
    int e = top_idx[tid];
    atomicAdd(&scnt[e], 1);
    __syncthreads();
    if (tid == 0) {
        int s = 0;
        for (int i = 0; i < 16; ++i) { spref[i] = s; pref[i] = s; cnt[i] = scnt[i]; s += scnt[i]; }
        int m1 = 0;
        for (int i = 0; i < 16; ++i) {
            int ntile1 = (scnt[i] + 15) >> 4;
            for (int m = 0; m < ntile1; ++m) tl1[m1++] = (i << 8) | m;
        }
        meta[0] = m1;
    }
    if (tid < 16) scur[tid] = 0;
    __syncthreads();
    int pos = spref[e] + atomicAdd(&scur[e], 1);
    slot[tid] = pos;
    invtok[pos] = tid >> 1;
    wslot[pos] = top_w[tid];
}

// gu GEMM + SwiGLU: MFMA, BK=64, dbuf LDS, 2-deep register prefetch + raw barriers.
__global__ __launch_bounds__(256) void gemm1_mfma(
    const float* __restrict__ x, const int* __restrict__ invtok,
    const int* __restrict__ qblk, const int* __restrict__ qscl,
    const float* __restrict__ bias,
    const int* __restrict__ cnt, const int* __restrict__ pref,
    const int* __restrict__ meta, const int* __restrict__ tl1,
    _Float16* __restrict__ hbuf) {
    __shared__ int lut[256];
    __shared__ int4 Asb[2][128];        // 16 tok x 8 int4 (fp16), dbuf (4 KB)
    __shared__ int4 Bsb[2][512];        // 64 rows x 8 int4, dbuf (16 KB)
    __shared__ float exch[4][64][4];    // 4 KB
    int tid = threadIdx.x;
    lut[tid] = fp4h(tid & 15) | (fp4h(tid >> 4) << 16);
    int wave = tid >> 6, lane = tid & 63;
    int bl = lane & 15, kb4 = lane >> 4;
    int rloc = wave * 16 + bl;
    int rs = tid >> 2, kq = tid & 3;    // B staging: row, k-quarter
    int tok = tid >> 4, jj = tid & 15;  // A staging: token, f32-int4 index
    int a2idx = (tok * 8 + ((jj >> 1) ^ (tok & 7))) * 2 + (jj & 1);
    int nwork = meta[0] << 6;

    for (int w = blockIdx.x; w < nwork; w += gridDim.x) {
        int tile = tl1[w >> 6];
        int fc = w & 63;
        int e = tile >> 8, mt = tile & 255;
        int n = cnt[e];
        int nt = n - mt * 16; if (nt > 16) nt = 16;
        int base = pref[e];
        int t0 = base + mt * 16;
        int f0 = fc * 32;

        long rowg = (long)e * 4096 + ((rs < 32) ? (f0 + rs) : (2048 + f0 + rs - 32));
        const int4* wrow = (const int4*)(qblk + rowg * 512);
        const int* srow = qscl + rowg * 32;
        int gtok = invtok[t0 + ((tok < nt) ? tok : nt - 1)];
        const int4* arow = (const int4*)x + (long)gtok * 256;   // f32 row = 256 int4

        // step 0 loads
        int4 c0q0 = wrow[kq * 2], c0q1 = wrow[kq * 2 + 1];
        int  c0sc = srow[kq >> 1];
        int4 c0av = arow[jj];
        __syncthreads();                 // lut ready + prev-item LDS retired
        stageA1(Asb[0], a2idx, c0av);
        stageB(lut, Bsb[0], rs, kq, c0q0, c0q1, c0sc);
        // prefetch steps 1 (RA), 2 (RB)
        int4 aq0 = wrow[8 + kq * 2], aq1 = wrow[8 + kq * 2 + 1];
        int  asc = srow[2 + (kq >> 1)];
        int4 aav = arow[16 + jj];
        int4 bq0 = wrow[16 + kq * 2], bq1 = wrow[16 + kq * 2 + 1];
        int  bsc = srow[4 + (kq >> 1)];
        int4 bav = arow[32 + jj];
        BARRIER_LDS();

        f32x4 acc = {0.f, 0.f, 0.f, 0.f};
        #pragma unroll
        for (int p = 0; p < 8; ++p) {
            int kb = 2 * p;
            // even step kb: compute buf0, stage step kb+1 (RA) -> buf1, load kb+3 -> RA
            #pragma unroll
            for (int ks = 0; ks < 2; ++ks) {
                int g = ks * 4 + kb4;
                XI a, b;
                a.v = Asb[0][bl * 8 + (g ^ (bl & 7))];
                b.v = Bsb[0][rloc * 8 + (g ^ (rloc & 7))];
                acc = __builtin_amdgcn_mfma_f32_16x16x32_f16(a.h, b.h, acc, 0, 0, 0);
            }
            stageA1(Asb[1], a2idx, aav);
            stageB(lut, Bsb[1], rs, kq, aq0, aq1, asc);
            if (p < 7) {
                int s = kb + 3;
                aq0 = wrow[s * 8 + kq * 2]; aq1 = wrow[s * 8 + kq * 2 + 1];
                asc = srow[s * 2 + (kq >> 1)];
                aav = arow[s * 16 + jj];
            }
            BARRIER_LDS();
            // odd step kb+1: compute buf1, stage step kb+2 (RB) -> buf0, load kb+4 -> RB
            #pragma unroll
            for (int ks = 0; ks < 2; ++ks) {
                int g = ks * 4 + kb4;
                XI a, b;
                a.v = Asb[1][bl * 8 + (g ^ (bl & 7))];
                b.v = Bsb[1][rloc * 8 + (g ^ (rloc & 7))];
                acc = __builtin_amdgcn_mfma_f32_16x16x32_f16(a.h, b.h, acc, 0, 0, 0);
            }
            if (p < 7) {
                stageA1(Asb[0], a2idx, bav);
                stageB(lut, Bsb[0], rs, kq, bq0, bq1, bsc);
                if (p < 6) {
                    int s = kb + 4;
                    bq0 = wrow[s * 8 + kq * 2]; bq1 = wrow[s * 8 + kq * 2 + 1];
                    bsc = srow[s * 2 + (kq >> 1)];
                    bav = arow[s * 16 + jj];
                }
            }
            BARRIER_LDS();
        }
        #pragma unroll
        for (int i = 0; i < 4; ++i) exch[wave][lane][i] = acc[i];
        __syncthreads();
        // epilogue: 16 tok x 32 f
        int fl = tid & 31, wv = fl >> 4, col = fl & 15;
        float bg = bias[(long)e * 4096 + f0 + fl];
        float bu = bias[(long)e * 4096 + 2048 + f0 + fl];
        #pragma unroll
        for (int d = 0; d < 2; ++d) {
            int tk = (tid >> 5) + d * 8;
            int ln = ((tk >> 2) << 4) | col;
            int rg = tk & 3;
            float g = exch[wv][ln][rg] + bg;
            float u = exch[wv + 2][ln][rg] + bu;
            float h = (g / (1.f + expf(-g))) * u;
            if (tk < nt)
                hbuf[(long)(t0 + tk) * FD + f0 + fl] = (_Float16)(h * 0.0625f);  // 2^-4
        }
        __syncthreads();   // protect LDS before next item's prologue
    }
}

// down GEMM: MFMA, BK=64, dbuf LDS, 2-deep prefetch + raw barriers; K split in 2
// halves; epilogue applies bias (kh==0) + routing weight and atomicAdds into out.
__global__ __launch_bounds__(256) void gemm2_mfma(
    const _Float16* __restrict__ hbuf, const int* __restrict__ qblk,
    const int* __restrict__ qscl, const float* __restrict__ bias,
    const int* __restrict__ cnt, const int* __restrict__ pref,
    const int* __restrict__ meta, const int* __restrict__ tl1,
    const int* __restrict__ invtok, const float* __restrict__ wslot,
    float* __restrict__ out) {
    __shared__ int lut[256];
    __shared__ int4 Asb[2][128];
    __shared__ int4 Bsb[2][512];
    int tid = threadIdx.x;
    lut[tid] = fp4h(tid & 15) | (fp4h(tid >> 4) << 16);
    int wave = tid >> 6, lane = tid & 63;
    int bl = lane & 15, kb4 = lane >> 4;
    int rloc = wave * 16 + bl;
    int rs = tid >> 2, kq = tid & 3;
    int tok = tid >> 3, ga = tid & 7;
    int aidx = tok * 8 + (ga ^ (tok & 7));
    int nwork = meta[0] << 5;           // 16 h-chunks x 2 k-halves

    for (int w = blockIdx.x; w < nwork; w += gridDim.x) {
        int tile = tl1[w >> 5];
        int sub = w & 31;
        int hc = sub & 15, kh = sub >> 4;
        int e = tile >> 8, mt = tile & 255;
        int n = cnt[e];
        int nt = n - mt * 16; if (nt > 16) nt = 16;
        int base = pref[e];
        int t0 = base + mt * 16;
        int h0 = hc * 64;

        long rowg = (long)e * HD + h0 + rs;
        const int4* wrow = (const int4*)(qblk + rowg * 1024) + (kh * 16) * 8;
        const int* srow = qscl + rowg * 64 + kh * 32;
        int tclamp = (tok < nt) ? tok : nt - 1;
        const int4* arow = (const int4*)hbuf + (long)(t0 + tclamp) * 256 + (kh * 16) * 8;

        int4 c0q0 = wrow[kq * 2], c0q1 = wrow[kq * 2 + 1];
        int  c0sc = srow[kq >> 1];
        int4 c0av;
        if (tid < 128) c0av = arow[ga];
        __syncthreads();
        if (tid < 128) Asb[0][aidx] = c0av;
        stageB(lut, Bsb[0], rs, kq, c0q0, c0q1, c0sc);
        int4 aq0 = wrow[8 + kq * 2], aq1 = wrow[8 + kq * 2 + 1];
        int  asc = srow[2 + (kq >> 1)];
        int4 aav; if (tid < 128) aav = arow[8 + ga];
        int4 bq0 = wrow[16 + kq * 2], bq1 = wrow[16 + kq * 2 + 1];
        int  bsc = srow[4 + (kq >> 1)];
        int4 bav; if (tid < 128) bav = arow[16 + ga];
        BARRIER_LDS();

        f32x4 acc = {0.f, 0.f, 0.f, 0.f};
        #pragma unroll
        for (int p = 0; p < 8; ++p) {
            int kb = 2 * p;
            #pragma unroll
            for (int ks = 0; ks < 2; ++ks) {
                int g = ks * 4 + kb4;
                XI a, b;
                a.v = Asb[0][bl * 8 + (g ^ (bl & 7))];
                b.v = Bsb[0][rloc * 8 + (g ^ (rloc & 7))];
                acc = __builtin_amdgcn_mfma_f32_16x16x32_f16(a.h, b.h, acc, 0, 0, 0);
            }
            if (tid < 128) Asb[1][aidx] = aav;
            stageB(lut, Bsb[1], rs, kq, aq0, aq1, asc);
            if (p < 7) {
                int s = kb + 3;
                aq0 = wrow[s * 8 + kq * 2]; aq1 = wrow[s * 8 + kq * 2 + 1];
                asc = srow[s * 2 + (kq >> 1)];
                if (tid < 128) aav = arow[s * 8 + ga];
            }
            BARRIER_LDS();
            #pragma unroll
            for (int ks = 0; ks < 2; ++ks) {
                int g = ks * 4 + kb4;
                XI a, b;
                a.v = Asb[1][bl * 8 + (g ^ (bl & 7))];
                b.v = Bsb[1][rloc * 8 + (g ^ (rloc & 7))];
                acc = __builtin_amdgcn_mfma_f32_16x16x32_f16(a.h, b.h, acc, 0, 0, 0);
            }
            if (p < 7) {
                if (tid < 128) Asb[0][aidx] = bav;
                stageB(lut, Bsb[0], rs, kq, bq0, bq1, bsc);
                if (p < 6) {
                    int s = kb + 4;
                    bq0 = wrow[s * 8 + kq * 2]; bq1 = wrow[s * 8 + kq * 2 + 1];
                    bsc = srow[s * 2 + (kq >> 1)];
                    if (tid < 128) bav = arow[s * 8 + ga];
                }
            }
            BARRIER_LDS();
        }
        // C: col=lane&15 -> h row; row=(lane>>4)*4+reg -> token slot
        int hcol = h0 + wave * 16 + bl;
        float bv = (kh == 0) ? bias[(long)e * HD + hcol] : 0.f;
        #pragma unroll
        for (int r = 0; r < 4; ++r) {
            int row = kb4 * 4 + r;
            if (row < nt) {
                int sl = t0 + row;
                float wgt = wslot[sl];
                atomicAdd(&out[(long)invtok[sl] * HD + hcol], wgt * (acc[r] * 16.f + bv));
            }
        }
        __syncthreads();   // protect LDS before next item's prologue writes
    }
}

extern "C" void kernel_launch(void* const* d_in, const int* in_sizes, int n_in,
                              void* d_out, int out_size, void* d_ws, size_t ws_size,
                              hipStream_t stream) {
    const float* x          = (const float*)d_in[0];
    const float* rw         = (const float*)d_in[1];
    const float* bias_gu    = (const float*)d_in[2];
    const float* bias_down  = (const float*)d_in[3];
    const int*   blocks_gu  = (const int*)d_in[4];
    const int*   scales_gu  = (const int*)d_in[5];
    const int*   blocks_down= (const int*)d_in[6];
    const int*   scales_down= (const int*)d_in[7];
    float* out = (float*)d_out;
    int*   wsI = (int*)d_ws;
    float* wsF = (float*)d_ws;
    _Float16* hbuf = (_Float16*)(wsI + HBUF_OFF);

    (void)hipMemsetAsync(out, 0, 128 * HD * sizeof(float), stream);
    routing_kernel<<<128, 256, 0, stream>>>(x, rw, wsI + TOPI_OFF, wsF + TOPW_OFF);
    build_kernel<<<1, 256, 0, stream>>>(wsI + TOPI_OFF, wsF + TOPW_OFF,
                                        wsI + CNT_OFF, wsI + PREF_OFF,
                                        wsI + SLOT_OFF, wsI + INVT_OFF, wsF + WSL_OFF,
                                        wsI + META_OFF, wsI + TL1_OFF);
    gemm1_mfma<<<2048, 256, 0, stream>>>(x, wsI + INVT_OFF, blocks_gu, scales_gu, bias_gu,
                                         wsI + CNT_OFF, wsI + PREF_OFF,
                                         wsI + META_OFF, wsI + TL1_OFF, hbuf);
    gemm2_mfma<<<1024, 256, 0, stream>>>(hbuf, blocks_down, scales_down, bias_down,
                                         wsI + CNT_OFF, wsI + PREF_OFF,
                                         wsI + META_OFF, wsI + TL1_OFF,
                                         wsI + INVT_OFF, wsF + WSL_OFF, out);
}

// Round 21
// 58.046 us; speedup vs baseline: 1.0635x; 1.0635x over previous
//
#include <hip/hip_runtime.h>
#include <hip/hip_fp16.h>
#include <math.h>

#define NE 16
#define HD 1024
#define FD 2048

typedef _Float16 half8 __attribute__((ext_vector_type(8)));
typedef float f32x4 __attribute__((ext_vector_type(4)));

// ws layout (4-byte units) — ws is ~512 MB, plenty.
#define TOPI_OFF 0          // 256 int
#define TOPW_OFF 256        // 256 float
#define CNT_OFF  512        // 16 int
#define PREF_OFF 528        // 16 int
#define SLOT_OFF 544        // 256 int (pair -> slot)
#define INVT_OFF 800        // 256 int (slot -> token)
#define META_OFF 1056       // 1 int: M1
#define TL1_OFF  1060       // 64 int  (e<<8|mt) 16-token tiles
#define HBUF_OFF 4096                   // h  fp16 [256][2048] = 262144 ints
#define Y0_OFF   (HBUF_OFF + 262144)    // y0 f32 [256][1024]
#define Y1_OFF   (Y0_OFF + 262144)      // y1 f32 [256][1024]

union XI { int4 v; half8 h; };

// raw workgroup barrier: LDS writes visible (lgkmcnt 0) but vector loads stay
// in flight (no vmcnt drain — the __syncthreads() drain is what caps prefetch depth)
#define BARRIER_LDS() asm volatile("s_waitcnt lgkmcnt(0)\ns_barrier" ::: "memory")

// fp4 e2m1 nibble -> fp16 bits (unscaled)
__device__ __forceinline__ int fp4h(int nib) {
    int c = nib & 7;
    int v;
    if (c == 0) v = 0;
    else if (c == 1) v = 14 << 10;                        // 0.5
    else v = (((c >> 1) + 14) << 10) | ((c & 1) << 9);
    v |= (nib & 8) << 12;
    return v;
}

// LUT byte -> 2 packed fp16 times packed pow2 scale (exact)
__device__ __forceinline__ int dec2i(const int* lut, int byte, int sv) {
    int l = lut[byte & 255];
    __half2 p = *reinterpret_cast<const __half2*>(&l);
    __half2 sc = *reinterpret_cast<const __half2*>(&sv);
    __half2 r = __hmul2(p, sc);
    return *reinterpret_cast<int*>(&r);
}

// decode 8 bytes (2 int4 of weights) + write swizzled to B tile
__device__ __forceinline__ void stageB(const int* lut, int4* Bbuf, int rs, int kq,
                                       int4 q0, int4 q1, int sc) {
    int sv = (sc - 112) << 10; sv |= sv << 16;
    int4 o0, o1;
    o0.x = dec2i(lut, q0.x, sv); o0.y = dec2i(lut, q0.y, sv);
    o0.z = dec2i(lut, q0.z, sv); o0.w = dec2i(lut, q0.w, sv);
    o1.x = dec2i(lut, q1.x, sv); o1.y = dec2i(lut, q1.y, sv);
    o1.z = dec2i(lut, q1.z, sv); o1.w = dec2i(lut, q1.w, sv);
    Bbuf[rs * 8 + ((kq * 2) ^ (rs & 7))] = o0;
    Bbuf[rs * 8 + ((kq * 2 + 1) ^ (rs & 7))] = o1;
}

// f32x4 -> 4 fp16 -> int2 write into A tile
__device__ __forceinline__ void stageA1(int4* Abuf, int a2idx, int4 av) {
    union { int4 v; float f[4]; } uf; uf.v = av;
    union { _Float16 h[4]; int2 p; } o;
    o.h[0] = (_Float16)uf.f[0]; o.h[1] = (_Float16)uf.f[1];
    o.h[2] = (_Float16)uf.f[2]; o.h[3] = (_Float16)uf.f[3];
    ((int2*)Abuf)[a2idx] = o.p;
}

__global__ void routing_kernel(const float* __restrict__ x, const float* __restrict__ rw,
                               int* __restrict__ top_idx, float* __restrict__ top_w) {
    int t = blockIdx.x;
    int tid = threadIdx.x;          // 256
    int e = tid >> 4, seg = tid & 15;
    const float4* xr = (const float4*)(x + t * HD + seg * 64);
    const float4* wr = (const float4*)(rw + e * HD + seg * 64);
    float p = 0.f;
    #pragma unroll
    for (int i = 0; i < 16; ++i) {
        float4 a = xr[i], b = wr[i];
        p = fmaf(a.x, b.x, fmaf(a.y, b.y, fmaf(a.z, b.z, fmaf(a.w, b.w, p))));
    }
    __shared__ float part[16][16];
    __shared__ float logit[16];
    part[e][seg] = p;
    __syncthreads();
    if (tid < 16) {
        float s = 0.f;
        #pragma unroll
        for (int i = 0; i < 16; ++i) s += part[tid][i];
        logit[tid] = s;
    }
    __syncthreads();
    if (tid == 0) {
        int i0 = 0; float v0 = logit[0];
        #pragma unroll
        for (int i = 1; i < 16; ++i) { if (logit[i] > v0) { v0 = logit[i]; i0 = i; } }
        int i1 = -1; float v1 = -1e30f;
        #pragma unroll
        for (int i = 0; i < 16; ++i) { if (i != i0 && logit[i] > v1) { v1 = logit[i]; i1 = i; } }
        float w0 = 1.f / (1.f + expf(v1 - v0));
        float w1 = 1.f / (1.f + expf(v0 - v1));
        top_idx[t * 2]     = i0;  top_w[t * 2]     = w0;
        top_idx[t * 2 + 1] = i1;  top_w[t * 2 + 1] = w1;
    }
}

__global__ void build_kernel(const int* __restrict__ top_idx,
                             int* __restrict__ cnt, int* __restrict__ pref,
                             int* __restrict__ slot, int* __restrict__ invtok,
                             int* __restrict__ meta, int* __restrict__ tl1) {
    __shared__ int scnt[16], spref[16], scur[16];
    int tid = threadIdx.x;          // 256
    if (tid < 16) scnt[tid] = 0;
    __syncthreads();
    int e = top_idx[tid];
    atomicAdd(&scnt[e], 1);
    __syncthreads();
    if (tid == 0) {
        int s = 0;
        for (int i = 0; i < 16; ++i) { spref[i] = s; pref[i] = s; cnt[i] = scnt[i]; s += scnt[i]; }
        int m1 = 0;
        for (int i = 0; i < 16; ++i) {
            int ntile1 = (scnt[i] + 15) >> 4;
            for (int m = 0; m < ntile1; ++m) tl1[m1++] = (i << 8) | m;
        }
        meta[0] = m1;
    }
    if (tid < 16) scur[tid] = 0;
    __syncthreads();
    int pos = spref[e] + atomicAdd(&scur[e], 1);
    slot[tid] = pos;
    invtok[pos] = tid >> 1;
}

// gu GEMM + SwiGLU: MFMA, BK=64, dbuf LDS, 2-deep register prefetch + raw barriers.
__global__ __launch_bounds__(256) void gemm1_mfma(
    const float* __restrict__ x, const int* __restrict__ invtok,
    const int* __restrict__ qblk, const int* __restrict__ qscl,
    const float* __restrict__ bias,
    const int* __restrict__ cnt, const int* __restrict__ pref,
    const int* __restrict__ meta, const int* __restrict__ tl1,
    _Float16* __restrict__ hbuf) {
    __shared__ int lut[256];
    __shared__ int4 Asb[2][128];        // 16 tok x 8 int4 (fp16), dbuf (4 KB)
    __shared__ int4 Bsb[2][512];        // 64 rows x 8 int4, dbuf (16 KB)
    __shared__ float exch[4][64][4];    // 4 KB
    int tid = threadIdx.x;
    lut[tid] = fp4h(tid & 15) | (fp4h(tid >> 4) << 16);
    int wave = tid >> 6, lane = tid & 63;
    int bl = lane & 15, kb4 = lane >> 4;
    int rloc = wave * 16 + bl;
    int rs = tid >> 2, kq = tid & 3;    // B staging: row, k-quarter
    int tok = tid >> 4, jj = tid & 15;  // A staging: token, f32-int4 index
    int a2idx = (tok * 8 + ((jj >> 1) ^ (tok & 7))) * 2 + (jj & 1);
    int nwork = meta[0] << 6;

    for (int w = blockIdx.x; w < nwork; w += gridDim.x) {
        int tile = tl1[w >> 6];
        int fc = w & 63;
        int e = tile >> 8, mt = tile & 255;
        int n = cnt[e];
        int nt = n - mt * 16; if (nt > 16) nt = 16;
        int base = pref[e];
        int t0 = base + mt * 16;
        int f0 = fc * 32;

        long rowg = (long)e * 4096 + ((rs < 32) ? (f0 + rs) : (2048 + f0 + rs - 32));
        const int4* wrow = (const int4*)(qblk + rowg * 512);
        const int* srow = qscl + rowg * 32;
        int gtok = invtok[t0 + ((tok < nt) ? tok : nt - 1)];
        const int4* arow = (const int4*)x + (long)gtok * 256;   // f32 row = 256 int4

        // step 0 loads
        int4 c0q0 = wrow[kq * 2], c0q1 = wrow[kq * 2 + 1];
        int  c0sc = srow[kq >> 1];
        int4 c0av = arow[jj];
        __syncthreads();                 // lut ready + prev-item LDS retired
        stageA1(Asb[0], a2idx, c0av);
        stageB(lut, Bsb[0], rs, kq, c0q0, c0q1, c0sc);
        // prefetch steps 1 (RA), 2 (RB)
        int4 aq0 = wrow[8 + kq * 2], aq1 = wrow[8 + kq * 2 + 1];
        int  asc = srow[2 + (kq >> 1)];
        int4 aav = arow[16 + jj];
        int4 bq0 = wrow[16 + kq * 2], bq1 = wrow[16 + kq * 2 + 1];
        int  bsc = srow[4 + (kq >> 1)];
        int4 bav = arow[32 + jj];
        BARRIER_LDS();

        f32x4 acc = {0.f, 0.f, 0.f, 0.f};
        #pragma unroll
        for (int p = 0; p < 8; ++p) {
            int kb = 2 * p;
            // even step kb: compute buf0, stage step kb+1 (RA) -> buf1, load kb+3 -> RA
            #pragma unroll
            for (int ks = 0; ks < 2; ++ks) {
                int g = ks * 4 + kb4;
                XI a, b;
                a.v = Asb[0][bl * 8 + (g ^ (bl & 7))];
                b.v = Bsb[0][rloc * 8 + (g ^ (rloc & 7))];
                acc = __builtin_amdgcn_mfma_f32_16x16x32_f16(a.h, b.h, acc, 0, 0, 0);
            }
            stageA1(Asb[1], a2idx, aav);
            stageB(lut, Bsb[1], rs, kq, aq0, aq1, asc);
            if (p < 7) {
                int s = kb + 3;
                aq0 = wrow[s * 8 + kq * 2]; aq1 = wrow[s * 8 + kq * 2 + 1];
                asc = srow[s * 2 + (kq >> 1)];
                aav = arow[s * 16 + jj];
            }
            BARRIER_LDS();
            // odd step kb+1: compute buf1, stage step kb+2 (RB) -> buf0, load kb+4 -> RB
            #pragma unroll
            for (int ks = 0; ks < 2; ++ks) {
                int g = ks * 4 + kb4;
                XI a, b;
                a.v = Asb[1][bl * 8 + (g ^ (bl & 7))];
                b.v = Bsb[1][rloc * 8 + (g ^ (rloc & 7))];
                acc = __builtin_amdgcn_mfma_f32_16x16x32_f16(a.h, b.h, acc, 0, 0, 0);
            }
            if (p < 7) {
                stageA1(Asb[0], a2idx, bav);
                stageB(lut, Bsb[0], rs, kq, bq0, bq1, bsc);
                if (p < 6) {
                    int s = kb + 4;
                    bq0 = wrow[s * 8 + kq * 2]; bq1 = wrow[s * 8 + kq * 2 + 1];
                    bsc = srow[s * 2 + (kq >> 1)];
                    bav = arow[s * 16 + jj];
                }
            }
            BARRIER_LDS();
        }
        #pragma unroll
        for (int i = 0; i < 4; ++i) exch[wave][lane][i] = acc[i];
        __syncthreads();
        // epilogue: 16 tok x 32 f
        int fl = tid & 31, wv = fl >> 4, col = fl & 15;
        float bg = bias[(long)e * 4096 + f0 + fl];
        float bu = bias[(long)e * 4096 + 2048 + f0 + fl];
        #pragma unroll
        for (int d = 0; d < 2; ++d) {
            int tk = (tid >> 5) + d * 8;
            int ln = ((tk >> 2) << 4) | col;
            int rg = tk & 3;
            float g = exch[wv][ln][rg] + bg;
            float u = exch[wv + 2][ln][rg] + bu;
            float h = (g / (1.f + expf(-g))) * u;
            if (tk < nt)
                hbuf[(long)(t0 + tk) * FD + f0 + fl] = (_Float16)(h * 0.0625f);  // 2^-4
        }
        __syncthreads();   // protect LDS before next item's prologue
    }
}

// down GEMM: MFMA, BK=64, dbuf LDS, 2-deep prefetch + raw barriers;
// K split in 2 halves -> y0/y1 (no atomics).
__global__ __launch_bounds__(256) void gemm2_mfma(
    const _Float16* __restrict__ hbuf, const int* __restrict__ qblk,
    const int* __restrict__ qscl, const float* __restrict__ bias,
    const int* __restrict__ cnt, const int* __restrict__ pref,
    const int* __restrict__ meta, const int* __restrict__ tl1,
    float* __restrict__ y0p, float* __restrict__ y1p) {
    __shared__ int lut[256];
    __shared__ int4 Asb[2][128];
    __shared__ int4 Bsb[2][512];
    int tid = threadIdx.x;
    lut[tid] = fp4h(tid & 15) | (fp4h(tid >> 4) << 16);
    int wave = tid >> 6, lane = tid & 63;
    int bl = lane & 15, kb4 = lane >> 4;
    int rloc = wave * 16 + bl;
    int rs = tid >> 2, kq = tid & 3;
    int tok = tid >> 3, ga = tid & 7;
    int aidx = tok * 8 + (ga ^ (tok & 7));
    int nwork = meta[0] << 5;           // 16 h-chunks x 2 k-halves

    for (int w = blockIdx.x; w < nwork; w += gridDim.x) {
        int tile = tl1[w >> 5];
        int sub = w & 31;
        int hc = sub & 15, kh = sub >> 4;
        int e = tile >> 8, mt = tile & 255;
        int n = cnt[e];
        int nt = n - mt * 16; if (nt > 16) nt = 16;
        int base = pref[e];
        int t0 = base + mt * 16;
        int h0 = hc * 64;

        long rowg = (long)e * HD + h0 + rs;
        const int4* wrow = (const int4*)(qblk + rowg * 1024) + (kh * 16) * 8;
        const int* srow = qscl + rowg * 64 + kh * 32;
        int tclamp = (tok < nt) ? tok : nt - 1;
        const int4* arow = (const int4*)hbuf + (long)(t0 + tclamp) * 256 + (kh * 16) * 8;

        int4 c0q0 = wrow[kq * 2], c0q1 = wrow[kq * 2 + 1];
        int  c0sc = srow[kq >> 1];
        int4 c0av;
        if (tid < 128) c0av = arow[ga];
        __syncthreads();
        if (tid < 128) Asb[0][aidx] = c0av;
        stageB(lut, Bsb[0], rs, kq, c0q0, c0q1, c0sc);
        int4 aq0 = wrow[8 + kq * 2], aq1 = wrow[8 + kq * 2 + 1];
        int  asc = srow[2 + (kq >> 1)];
        int4 aav; if (tid < 128) aav = arow[8 + ga];
        int4 bq0 = wrow[16 + kq * 2], bq1 = wrow[16 + kq * 2 + 1];
        int  bsc = srow[4 + (kq >> 1)];
        int4 bav; if (tid < 128) bav = arow[16 + ga];
        BARRIER_LDS();

        f32x4 acc = {0.f, 0.f, 0.f, 0.f};
        #pragma unroll
        for (int p = 0; p < 8; ++p) {
            int kb = 2 * p;
            #pragma unroll
            for (int ks = 0; ks < 2; ++ks) {
                int g = ks * 4 + kb4;
                XI a, b;
                a.v = Asb[0][bl * 8 + (g ^ (bl & 7))];
                b.v = Bsb[0][rloc * 8 + (g ^ (rloc & 7))];
                acc = __builtin_amdgcn_mfma_f32_16x16x32_f16(a.h, b.h, acc, 0, 0, 0);
            }
            if (tid < 128) Asb[1][aidx] = aav;
            stageB(lut, Bsb[1], rs, kq, aq0, aq1, asc);
            if (p < 7) {
                int s = kb + 3;
                aq0 = wrow[s * 8 + kq * 2]; aq1 = wrow[s * 8 + kq * 2 + 1];
                asc = srow[s * 2 + (kq >> 1)];
                if (tid < 128) aav = arow[s * 8 + ga];
            }
            BARRIER_LDS();
            #pragma unroll
            for (int ks = 0; ks < 2; ++ks) {
                int g = ks * 4 + kb4;
                XI a, b;
                a.v = Asb[1][bl * 8 + (g ^ (bl & 7))];
                b.v = Bsb[1][rloc * 8 + (g ^ (rloc & 7))];
                acc = __builtin_amdgcn_mfma_f32_16x16x32_f16(a.h, b.h, acc, 0, 0, 0);
            }
            if (p < 7) {
                if (tid < 128) Asb[0][aidx] = bav;
                stageB(lut, Bsb[0], rs, kq, bq0, bq1, bsc);
                if (p < 6) {
                    int s = kb + 4;
                    bq0 = wrow[s * 8 + kq * 2]; bq1 = wrow[s * 8 + kq * 2 + 1];
                    bsc = srow[s * 2 + (kq >> 1)];
                    if (tid < 128) bav = arow[s * 8 + ga];
                }
            }
            BARRIER_LDS();
        }
        // C: col=lane&15 -> h row; row=(lane>>4)*4+reg -> token
        int hcol = h0 + wave * 16 + bl;
        float bv = (kh == 0) ? bias[(long)e * HD + hcol] : 0.f;
        float* yp = (kh == 0) ? y0p : y1p;
        #pragma unroll
        for (int r = 0; r < 4; ++r) {
            int row = kb4 * 4 + r;
            if (row < nt)
                yp[(long)(t0 + row) * HD + hcol] = acc[r] * 16.f + bv;
        }
        __syncthreads();   // protect LDS before next item's prologue writes
    }
}

__global__ void combine_kernel(const float* __restrict__ y0, const float* __restrict__ y1,
                               const int* __restrict__ slot, const float* __restrict__ topw,
                               float* __restrict__ out) {
    int t = blockIdx.x;
    int i = threadIdx.x;   // 256, float4 each
    int s0 = slot[2 * t], s1 = slot[2 * t + 1];
    float w0 = topw[2 * t], w1 = topw[2 * t + 1];
    float4 a0 = ((const float4*)(y0 + (long)s0 * HD))[i];
    float4 a1 = ((const float4*)(y1 + (long)s0 * HD))[i];
    float4 b0 = ((const float4*)(y0 + (long)s1 * HD))[i];
    float4 b1 = ((const float4*)(y1 + (long)s1 * HD))[i];
    float4 o;
    o.x = w0 * (a0.x + a1.x) + w1 * (b0.x + b1.x);
    o.y = w0 * (a0.y + a1.y) + w1 * (b0.y + b1.y);
    o.z = w0 * (a0.z + a1.z) + w1 * (b0.z + b1.z);
    o.w = w0 * (a0.w + a1.w) + w1 * (b0.w + b1.w);
    ((float4*)(out + (long)t * HD))[i] = o;
}

extern "C" void kernel_launch(void* const* d_in, const int* in_sizes, int n_in,
                              void* d_out, int out_size, void* d_ws, size_t ws_size,
                              hipStream_t stream) {
    const float* x          = (const float*)d_in[0];
    const float* rw         = (const float*)d_in[1];
    const float* bias_gu    = (const float*)d_in[2];
    const float* bias_down  = (const float*)d_in[3];
    const int*   blocks_gu  = (const int*)d_in[4];
    const int*   scales_gu  = (const int*)d_in[5];
    const int*   blocks_down= (const int*)d_in[6];
    const int*   scales_down= (const int*)d_in[7];
    float* out = (float*)d_out;
    int*   wsI = (int*)d_ws;
    float* wsF = (float*)d_ws;
    _Float16* hbuf = (_Float16*)(wsI + HBUF_OFF);
    float*    y0   = wsF + Y0_OFF;
    float*    y1   = wsF + Y1_OFF;

    routing_kernel<<<128, 256, 0, stream>>>(x, rw, wsI + TOPI_OFF, wsF + TOPW_OFF);
    build_kernel<<<1, 256, 0, stream>>>(wsI + TOPI_OFF, wsI + CNT_OFF, wsI + PREF_OFF,
                                        wsI + SLOT_OFF, wsI + INVT_OFF,
                                        wsI + META_OFF, wsI + TL1_OFF);
    gemm1_mfma<<<2048, 256, 0, stream>>>(x, wsI + INVT_OFF, blocks_gu, scales_gu, bias_gu,
                                         wsI + CNT_OFF, wsI + PREF_OFF,
                                         wsI + META_OFF, wsI + TL1_OFF, hbuf);
    gemm2_mfma<<<1024, 256, 0, stream>>>(hbuf, blocks_down, scales_down, bias_down,
                                         wsI + CNT_OFF, wsI + PREF_OFF,
                                         wsI + META_OFF, wsI + TL1_OFF, y0, y1);
    combine_kernel<<<128, 256, 0, stream>>>(y0, y1, wsI + SLOT_OFF, wsF + TOPW_OFF, out);
}

// Round 22
// 55.532 us; speedup vs baseline: 1.1116x; 1.0453x over previous
//
#include <hip/hip_runtime.h>
#include <hip/hip_fp16.h>
#include <math.h>

#define NE 16
#define HD 1024
#define FD 2048

typedef _Float16 half8 __attribute__((ext_vector_type(8)));
typedef float f32x4 __attribute__((ext_vector_type(4)));

// ws layout (4-byte units)
#define TOPI_OFF 0          // 256 int
#define TOPW_OFF 256        // 256 float
#define CNT_OFF  512        // 16 int
#define PREF_OFF 528        // 16 int
#define SLOT_OFF 544        // 256 int (pair -> slot)
#define INVT_OFF 800        // 256 int (slot -> token)
#define META_OFF 1056       // 1 int: M32
#define TL1_OFF  1060       // 64 int  (e<<8|mt) 32-token tiles
#define HBUF_OFF 4096                   // h  fp16 [256][2048] = 262144 ints
#define Y0_OFF   (HBUF_OFF + 262144)    // y0 f32 [256][1024]
#define Y1_OFF   (Y0_OFF + 262144)      // y1 f32 [256][1024]

union XI { int4 v; half8 h; };

// raw workgroup barrier: LDS writes visible (lgkmcnt 0) but vector loads stay in flight
#define BARRIER_LDS() asm volatile("s_waitcnt lgkmcnt(0)\ns_barrier" ::: "memory")

// fp4 e2m1 nibble -> fp16 bits (unscaled)
__device__ __forceinline__ int fp4h(int nib) {
    int c = nib & 7;
    int v;
    if (c == 0) v = 0;
    else if (c == 1) v = 14 << 10;                        // 0.5
    else v = (((c >> 1) + 14) << 10) | ((c & 1) << 9);
    v |= (nib & 8) << 12;
    return v;
}

// LUT byte -> 2 packed fp16 times packed pow2 scale (exact)
__device__ __forceinline__ int dec2i(const int* lut, int byte, int sv) {
    int l = lut[byte & 255];
    __half2 p = *reinterpret_cast<const __half2*>(&l);
    __half2 sc = *reinterpret_cast<const __half2*>(&sv);
    __half2 r = __hmul2(p, sc);
    return *reinterpret_cast<int*>(&r);
}

// decode 8 bytes (2 int4 of weights) + write swizzled to B tile
__device__ __forceinline__ void stageB(const int* lut, int4* Bbuf, int rs, int kq,
                                       int4 q0, int4 q1, int sc) {
    int sv = (sc - 112) << 10; sv |= sv << 16;
    int4 o0, o1;
    o0.x = dec2i(lut, q0.x, sv); o0.y = dec2i(lut, q0.y, sv);
    o0.z = dec2i(lut, q0.z, sv); o0.w = dec2i(lut, q0.w, sv);
    o1.x = dec2i(lut, q1.x, sv); o1.y = dec2i(lut, q1.y, sv);
    o1.z = dec2i(lut, q1.z, sv); o1.w = dec2i(lut, q1.w, sv);
    Bbuf[rs * 8 + ((kq * 2) ^ (rs & 7))] = o0;
    Bbuf[rs * 8 + ((kq * 2 + 1) ^ (rs & 7))] = o1;
}

// 2 f32-int4 -> 8 fp16 -> one int4 write into A tile
__device__ __forceinline__ void stageA2(int4* Abuf, int aidx, int4 av0, int4 av1) {
    union { int4 v; float f[4]; } u0, u1; u0.v = av0; u1.v = av1;
    union { _Float16 h[8]; int4 p; } o;
    o.h[0] = (_Float16)u0.f[0]; o.h[1] = (_Float16)u0.f[1];
    o.h[2] = (_Float16)u0.f[2]; o.h[3] = (_Float16)u0.f[3];
    o.h[4] = (_Float16)u1.f[0]; o.h[5] = (_Float16)u1.f[1];
    o.h[6] = (_Float16)u1.f[2]; o.h[7] = (_Float16)u1.f[3];
    Abuf[aidx] = o.p;
}

__global__ void routing_kernel(const float* __restrict__ x, const float* __restrict__ rw,
                               int* __restrict__ top_idx, float* __restrict__ top_w) {
    int t = blockIdx.x;
    int tid = threadIdx.x;          // 256
    int e = tid >> 4, seg = tid & 15;
    const float4* xr = (const float4*)(x + t * HD + seg * 64);
    const float4* wr = (const float4*)(rw + e * HD + seg * 64);
    float p = 0.f;
    #pragma unroll
    for (int i = 0; i < 16; ++i) {
        float4 a = xr[i], b = wr[i];
        p = fmaf(a.x, b.x, fmaf(a.y, b.y, fmaf(a.z, b.z, fmaf(a.w, b.w, p))));
    }
    __shared__ float part[16][16];
    __shared__ float logit[16];
    part[e][seg] = p;
    __syncthreads();
    if (tid < 16) {
        float s = 0.f;
        #pragma unroll
        for (int i = 0; i < 16; ++i) s += part[tid][i];
        logit[tid] = s;
    }
    __syncthreads();
    if (tid == 0) {
        int i0 = 0; float v0 = logit[0];
        #pragma unroll
        for (int i = 1; i < 16; ++i) { if (logit[i] > v0) { v0 = logit[i]; i0 = i; } }
        int i1 = -1; float v1 = -1e30f;
        #pragma unroll
        for (int i = 0; i < 16; ++i) { if (i != i0 && logit[i] > v1) { v1 = logit[i]; i1 = i; } }
        float w0 = 1.f / (1.f + expf(v1 - v0));
        float w1 = 1.f / (1.f + expf(v0 - v1));
        top_idx[t * 2]     = i0;  top_w[t * 2]     = w0;
        top_idx[t * 2 + 1] = i1;  top_w[t * 2 + 1] = w1;
    }
}

__global__ void build_kernel(const int* __restrict__ top_idx,
                             int* __restrict__ cnt, int* __restrict__ pref,
                             int* __restrict__ slot, int* __restrict__ invtok,
                             int* __restrict__ meta, int* __restrict__ tl1) {
    __shared__ int scnt[16], spref[16], scur[16];
    int tid = threadIdx.x;          // 256
    if (tid < 16) scnt[tid] = 0;
    __syncthreads();
    int e = top_idx[tid];
    atomicAdd(&scnt[e], 1);
    __syncthreads();
    if (tid == 0) {
        int s = 0;
        for (int i = 0; i < 16; ++i) { spref[i] = s; pref[i] = s; cnt[i] = scnt[i]; s += scnt[i]; }
        int m1 = 0;
        for (int i = 0; i < 16; ++i) {
            int ntile = (scnt[i] + 31) >> 5;     // 32-token tiles
            for (int m = 0; m < ntile; ++m) tl1[m1++] = (i << 8) | m;
        }
        meta[0] = m1;
    }
    if (tid < 16) scur[tid] = 0;
    __syncthreads();
    int pos = spref[e] + atomicAdd(&scur[e], 1);
    slot[tid] = pos;
    invtok[pos] = tid >> 1;
}

// gu GEMM + SwiGLU: MFMA, BK=64, M=32 tokens (dual acc), dbuf LDS,
// 2-deep register prefetch + raw barriers. Weights fetched+decoded once.
__global__ __launch_bounds__(256) void gemm1_mfma(
    const float* __restrict__ x, const int* __restrict__ invtok,
    const int* __restrict__ qblk, const int* __restrict__ qscl,
    const float* __restrict__ bias,
    const int* __restrict__ cnt, const int* __restrict__ pref,
    const int* __restrict__ meta, const int* __restrict__ tl1,
    _Float16* __restrict__ hbuf) {
    __shared__ int lut[256];
    __shared__ int4 Asb[2][256];        // 32 tok x 8 int4 (fp16), dbuf (8 KB)
    __shared__ int4 Bsb[2][512];        // 64 rows x 8 int4, dbuf (16 KB)
    __shared__ float exch[4][64][8];    // 8 KB
    int tid = threadIdx.x;
    lut[tid] = fp4h(tid & 15) | (fp4h(tid >> 4) << 16);
    int wave = tid >> 6, lane = tid & 63;
    int bl = lane & 15, kb4 = lane >> 4;
    int rloc = wave * 16 + bl;
    int rs = tid >> 2, kq = tid & 3;    // B staging: row, k-quarter
    int tokA = tid >> 3, ja = tid & 7;  // A staging: token (0..31), fp16-int4 index
    int aidx = tokA * 8 + (ja ^ (tokA & 7));
    int nwork = meta[0] << 6;

    for (int w = blockIdx.x; w < nwork; w += gridDim.x) {
        int tile = tl1[w >> 6];
        int fc = w & 63;
        int e = tile >> 8, mt = tile & 255;
        int n = cnt[e];
        int nt = n - mt * 32; if (nt > 32) nt = 32;
        int base = pref[e];
        int t0 = base + mt * 32;
        int f0 = fc * 32;

        long rowg = (long)e * 4096 + ((rs < 32) ? (f0 + rs) : (2048 + f0 + rs - 32));
        const int4* wrow = (const int4*)(qblk + rowg * 512);
        const int* srow = qscl + rowg * 32;
        int gtok = invtok[t0 + ((tokA < nt) ? tokA : nt - 1)];
        const int4* arow = (const int4*)x + (long)gtok * 256;   // f32 row = 256 int4

        // step 0 loads
        int4 c0q0 = wrow[kq * 2], c0q1 = wrow[kq * 2 + 1];
        int  c0sc = srow[kq >> 1];
        int4 c0a0 = arow[ja * 2], c0a1 = arow[ja * 2 + 1];
        __syncthreads();                 // lut ready + prev-item LDS retired
        stageA2(Asb[0], aidx, c0a0, c0a1);
        stageB(lut, Bsb[0], rs, kq, c0q0, c0q1, c0sc);
        // prefetch steps 1 (RA), 2 (RB)
        int4 aq0 = wrow[8 + kq * 2], aq1 = wrow[8 + kq * 2 + 1];
        int  asc = srow[2 + (kq >> 1)];
        int4 aa0 = arow[16 + ja * 2], aa1 = arow[16 + ja * 2 + 1];
        int4 bq0 = wrow[16 + kq * 2], bq1 = wrow[16 + kq * 2 + 1];
        int  bsc = srow[4 + (kq >> 1)];
        int4 ba0 = arow[32 + ja * 2], ba1 = arow[32 + ja * 2 + 1];
        BARRIER_LDS();

        f32x4 acc0 = {0.f, 0.f, 0.f, 0.f}, acc1 = {0.f, 0.f, 0.f, 0.f};
        #pragma unroll
        for (int p = 0; p < 8; ++p) {
            int kb = 2 * p;
            #pragma unroll
            for (int ks = 0; ks < 2; ++ks) {
                int g = ks * 4 + kb4;
                XI a0, a1, b;
                b.v = Bsb[0][rloc * 8 + (g ^ (rloc & 7))];
                a0.v = Asb[0][bl * 8 + (g ^ (bl & 7))];
                a1.v = Asb[0][(16 + bl) * 8 + (g ^ (bl & 7))];
                acc0 = __builtin_amdgcn_mfma_f32_16x16x32_f16(a0.h, b.h, acc0, 0, 0, 0);
                acc1 = __builtin_amdgcn_mfma_f32_16x16x32_f16(a1.h, b.h, acc1, 0, 0, 0);
            }
            stageA2(Asb[1], aidx, aa0, aa1);
            stageB(lut, Bsb[1], rs, kq, aq0, aq1, asc);
            if (p < 7) {
                int s = kb + 3;
                aq0 = wrow[s * 8 + kq * 2]; aq1 = wrow[s * 8 + kq * 2 + 1];
                asc = srow[s * 2 + (kq >> 1)];
                aa0 = arow[s * 16 + ja * 2]; aa1 = arow[s * 16 + ja * 2 + 1];
            }
            BARRIER_LDS();
            #pragma unroll
            for (int ks = 0; ks < 2; ++ks) {
                int g = ks * 4 + kb4;
                XI a0, a1, b;
                b.v = Bsb[1][rloc * 8 + (g ^ (rloc & 7))];
                a0.v = Asb[1][bl * 8 + (g ^ (bl & 7))];
                a1.v = Asb[1][(16 + bl) * 8 + (g ^ (bl & 7))];
                acc0 = __builtin_amdgcn_mfma_f32_16x16x32_f16(a0.h, b.h, acc0, 0, 0, 0);
                acc1 = __builtin_amdgcn_mfma_f32_16x16x32_f16(a1.h, b.h, acc1, 0, 0, 0);
            }
            if (p < 7) {
                stageA2(Asb[0], aidx, ba0, ba1);
                stageB(lut, Bsb[0], rs, kq, bq0, bq1, bsc);
                if (p < 6) {
                    int s = kb + 4;
                    bq0 = wrow[s * 8 + kq * 2]; bq1 = wrow[s * 8 + kq * 2 + 1];
                    bsc = srow[s * 2 + (kq >> 1)];
                    ba0 = arow[s * 16 + ja * 2]; ba1 = arow[s * 16 + ja * 2 + 1];
                }
            }
            BARRIER_LDS();
        }
        #pragma unroll
        for (int i = 0; i < 4; ++i) {
            exch[wave][lane][i] = acc0[i];
            exch[wave][lane][4 + i] = acc1[i];
        }
        __syncthreads();
        // epilogue: 32 tok x 32 f; thread: fl = tid&31, tokens (tid>>5)+d*8, d=0..3
        int fl = tid & 31, wv = fl >> 4, col = fl & 15;
        float bg = bias[(long)e * 4096 + f0 + fl];
        float bu = bias[(long)e * 4096 + 2048 + f0 + fl];
        #pragma unroll
        for (int d = 0; d < 4; ++d) {
            int tk = (tid >> 5) + d * 8;     // 0..31
            int tr = tk & 15;
            int ln = ((tr >> 2) << 4) | col;
            int rg = (tr & 3) + ((tk >= 16) ? 4 : 0);
            float g = exch[wv][ln][rg] + bg;
            float u = exch[wv + 2][ln][rg] + bu;
            float h = (g / (1.f + expf(-g))) * u;
            if (tk < nt)
                hbuf[(long)(t0 + tk) * FD + f0 + fl] = (_Float16)(h * 0.0625f);  // 2^-4
        }
        __syncthreads();   // protect LDS before next item's prologue
    }
}

// down GEMM: MFMA, BK=64, M=32 tokens (dual acc), dbuf LDS, 2-deep prefetch +
// raw barriers; K split in 2 halves -> y0/y1 (no atomics).
__global__ __launch_bounds__(256) void gemm2_mfma(
    const _Float16* __restrict__ hbuf, const int* __restrict__ qblk,
    const int* __restrict__ qscl, const float* __restrict__ bias,
    const int* __restrict__ cnt, const int* __restrict__ pref,
    const int* __restrict__ meta, const int* __restrict__ tl1,
    float* __restrict__ y0p, float* __restrict__ y1p) {
    __shared__ int lut[256];
    __shared__ int4 Asb[2][256];        // 32 tok x 8 int4 (8 KB)
    __shared__ int4 Bsb[2][512];
    int tid = threadIdx.x;
    lut[tid] = fp4h(tid & 15) | (fp4h(tid >> 4) << 16);
    int wave = tid >> 6, lane = tid & 63;
    int bl = lane & 15, kb4 = lane >> 4;
    int rloc = wave * 16 + bl;
    int rs = tid >> 2, kq = tid & 3;
    int tokA = tid >> 3, ga = tid & 7;
    int aidx = tokA * 8 + (ga ^ (tokA & 7));
    int nwork = meta[0] << 5;           // 16 h-chunks x 2 k-halves

    for (int w = blockIdx.x; w < nwork; w += gridDim.x) {
        int tile = tl1[w >> 5];
        int sub = w & 31;
        int hc = sub & 15, kh = sub >> 4;
        int e = tile >> 8, mt = tile & 255;
        int n = cnt[e];
        int nt = n - mt * 32; if (nt > 32) nt = 32;
        int base = pref[e];
        int t0 = base + mt * 32;
        int h0 = hc * 64;

        long rowg = (long)e * HD + h0 + rs;
        const int4* wrow = (const int4*)(qblk + rowg * 1024) + (kh * 16) * 8;
        const int* srow = qscl + rowg * 64 + kh * 32;
        int tclamp = (tokA < nt) ? tokA : nt - 1;
        const int4* arow = (const int4*)hbuf + (long)(t0 + tclamp) * 256 + kh * 128;

        int4 c0q0 = wrow[kq * 2], c0q1 = wrow[kq * 2 + 1];
        int  c0sc = srow[kq >> 1];
        int4 c0av = arow[ga];
        __syncthreads();
        Asb[0][aidx] = c0av;
        stageB(lut, Bsb[0], rs, kq, c0q0, c0q1, c0sc);
        int4 aq0 = wrow[8 + kq * 2], aq1 = wrow[8 + kq * 2 + 1];
        int  asc = srow[2 + (kq >> 1)];
        int4 aav = arow[8 + ga];
        int4 bq0 = wrow[16 + kq * 2], bq1 = wrow[16 + kq * 2 + 1];
        int  bsc = srow[4 + (kq >> 1)];
        int4 bav = arow[16 + ga];
        BARRIER_LDS();

        f32x4 acc0 = {0.f, 0.f, 0.f, 0.f}, acc1 = {0.f, 0.f, 0.f, 0.f};
        #pragma unroll
        for (int p = 0; p < 8; ++p) {
            int kb = 2 * p;
            #pragma unroll
            for (int ks = 0; ks < 2; ++ks) {
                int g = ks * 4 + kb4;
                XI a0, a1, b;
                b.v = Bsb[0][rloc * 8 + (g ^ (rloc & 7))];
                a0.v = Asb[0][bl * 8 + (g ^ (bl & 7))];
                a1.v = Asb[0][(16 + bl) * 8 + (g ^ (bl & 7))];
                acc0 = __builtin_amdgcn_mfma_f32_16x16x32_f16(a0.h, b.h, acc0, 0, 0, 0);
                acc1 = __builtin_amdgcn_mfma_f32_16x16x32_f16(a1.h, b.h, acc1, 0, 0, 0);
            }
            Asb[1][aidx] = aav;
            stageB(lut, Bsb[1], rs, kq, aq0, aq1, asc);
            if (p < 7) {
                int s = kb + 3;
                aq0 = wrow[s * 8 + kq * 2]; aq1 = wrow[s * 8 + kq * 2 + 1];
                asc = srow[s * 2 + (kq >> 1)];
                aav = arow[s * 8 + ga];
            }
            BARRIER_LDS();
            #pragma unroll
            for (int ks = 0; ks < 2; ++ks) {
                int g = ks * 4 + kb4;
                XI a0, a1, b;
                b.v = Bsb[1][rloc * 8 + (g ^ (rloc & 7))];
                a0.v = Asb[1][bl * 8 + (g ^ (bl & 7))];
                a1.v = Asb[1][(16 + bl) * 8 + (g ^ (bl & 7))];
                acc0 = __builtin_amdgcn_mfma_f32_16x16x32_f16(a0.h, b.h, acc0, 0, 0, 0);
                acc1 = __builtin_amdgcn_mfma_f32_16x16x32_f16(a1.h, b.h, acc1, 0, 0, 0);
            }
            if (p < 7) {
                Asb[0][aidx] = bav;
                stageB(lut, Bsb[0], rs, kq, bq0, bq1, bsc);
                if (p < 6) {
                    int s = kb + 4;
                    bq0 = wrow[s * 8 + kq * 2]; bq1 = wrow[s * 8 + kq * 2 + 1];
                    bsc = srow[s * 2 + (kq >> 1)];
                    bav = arow[s * 8 + ga];
                }
            }
            BARRIER_LDS();
        }
        // C: col=lane&15 -> h row; token rows: acc0 -> kb4*4+r, acc1 -> 16+kb4*4+r
        int hcol = h0 + wave * 16 + bl;
        float bv = (kh == 0) ? bias[(long)e * HD + hcol] : 0.f;
        float* yp = (kh == 0) ? y0p : y1p;
        #pragma unroll
        for (int r = 0; r < 4; ++r) {
            int row0 = kb4 * 4 + r;
            if (row0 < nt)
                yp[(long)(t0 + row0) * HD + hcol] = acc0[r] * 16.f + bv;
            int row1 = 16 + kb4 * 4 + r;
            if (row1 < nt)
                yp[(long)(t0 + row1) * HD + hcol] = acc1[r] * 16.f + bv;
        }
        __syncthreads();   // protect LDS before next item's prologue writes
    }
}

__global__ void combine_kernel(const float* __restrict__ y0, const float* __restrict__ y1,
                               const int* __restrict__ slot, const float* __restrict__ topw,
                               float* __restrict__ out) {
    int t = blockIdx.x;
    int i = threadIdx.x;   // 256, float4 each
    int s0 = slot[2 * t], s1 = slot[2 * t + 1];
    float w0 = topw[2 * t], w1 = topw[2 * t + 1];
    float4 a0 = ((const float4*)(y0 + (long)s0 * HD))[i];
    float4 a1 = ((const float4*)(y1 + (long)s0 * HD))[i];
    float4 b0 = ((const float4*)(y0 + (long)s1 * HD))[i];
    float4 b1 = ((const float4*)(y1 + (long)s1 * HD))[i];
    float4 o;
    o.x = w0 * (a0.x + a1.x) + w1 * (b0.x + b1.x);
    o.y = w0 * (a0.y + a1.y) + w1 * (b0.y + b1.y);
    o.z = w0 * (a0.z + a1.z) + w1 * (b0.z + b1.z);
    o.w = w0 * (a0.w + a1.w) + w1 * (b0.w + b1.w);
    ((float4*)(out + (long)t * HD))[i] = o;
}

extern "C" void kernel_launch(void* const* d_in, const int* in_sizes, int n_in,
                              void* d_out, int out_size, void* d_ws, size_t ws_size,
                              hipStream_t stream) {
    const float* x          = (const float*)d_in[0];
    const float* rw         = (const float*)d_in[1];
    const float* bias_gu    = (const float*)d_in[2];
    const float* bias_down  = (const float*)d_in[3];
    const int*   blocks_gu  = (const int*)d_in[4];
    const int*   scales_gu  = (const int*)d_in[5];
    const int*   blocks_down= (const int*)d_in[6];
    const int*   scales_down= (const int*)d_in[7];
    float* out = (float*)d_out;
    int*   wsI = (int*)d_ws;
    float* wsF = (float*)d_ws;
    _Float16* hbuf = (_Float16*)(wsI + HBUF_OFF);
    float*    y0   = wsF + Y0_OFF;
    float*    y1   = wsF + Y1_OFF;

    routing_kernel<<<128, 256, 0, stream>>>(x, rw, wsI + TOPI_OFF, wsF + TOPW_OFF);
    build_kernel<<<1, 256, 0, stream>>>(wsI + TOPI_OFF, wsI + CNT_OFF, wsI + PREF_OFF,
                                        wsI + SLOT_OFF, wsI + INVT_OFF,
                                        wsI + META_OFF, wsI + TL1_OFF);
    gemm1_mfma<<<1024, 256, 0, stream>>>(x, wsI + INVT_OFF, blocks_gu, scales_gu, bias_gu,
                                         wsI + CNT_OFF, wsI + PREF_OFF,
                                         wsI + META_OFF, wsI + TL1_OFF, hbuf);
    gemm2_mfma<<<512, 256, 0, stream>>>(hbuf, blocks_down, scales_down, bias_down,
                                        wsI + CNT_OFF, wsI + PREF_OFF,
                                        wsI + META_OFF, wsI + TL1_OFF, y0, y1);
    combine_kernel<<<128, 256, 0, stream>>>(y0, y1, wsI + SLOT_OFF, wsF + TOPW_OFF, out);
}

// Round 23
// 55.529 us; speedup vs baseline: 1.1117x; 1.0001x over previous
//
#include <hip/hip_runtime.h>
#include <hip/hip_fp16.h>
#include <math.h>

#define NE 16
#define HD 1024
#define FD 2048

typedef _Float16 half8 __attribute__((ext_vector_type(8)));
typedef float f32x4 __attribute__((ext_vector_type(4)));

// ws layout (4-byte units)
#define TOPI_OFF 0          // 256 int
#define TOPW_OFF 256        // 256 float
#define CNT_OFF  512        // 16 int
#define PREF_OFF 528        // 16 int
#define SLOT_OFF 544        // 256 int (pair -> slot)
#define INVT_OFF 800        // 256 int (slot -> token)
#define META_OFF 1056       // 1 int: M32
#define TL1_OFF  1060       // 64 int  (e<<8|mt) 32-token tiles
#define HBUF_OFF 4096                   // h  fp16 [256][2048] = 262144 ints
#define Y0_OFF   (HBUF_OFF + 262144)    // y0 f32 [256][1024]
#define Y1_OFF   (Y0_OFF + 262144)      // y1 f32 [256][1024]

union XI { int4 v; half8 h; };

// raw workgroup barrier: LDS writes visible (lgkmcnt 0) but vector loads stay in flight
#define BARRIER_LDS() asm volatile("s_waitcnt lgkmcnt(0)\ns_barrier" ::: "memory")

// fp4 e2m1 nibble -> fp16 bits (unscaled)
__device__ __forceinline__ int fp4h(int nib) {
    int c = nib & 7;
    int v;
    if (c == 0) v = 0;
    else if (c == 1) v = 14 << 10;                        // 0.5
    else v = (((c >> 1) + 14) << 10) | ((c & 1) << 9);
    v |= (nib & 8) << 12;
    return v;
}

// LUT byte -> 2 packed fp16 times packed pow2 scale (exact)
__device__ __forceinline__ int dec2i(const int* lut, int byte, int sv) {
    int l = lut[byte & 255];
    __half2 p = *reinterpret_cast<const __half2*>(&l);
    __half2 sc = *reinterpret_cast<const __half2*>(&sv);
    __half2 r = __hmul2(p, sc);
    return *reinterpret_cast<int*>(&r);
}

// decode 8 bytes (2 int4 of weights) + write swizzled to B tile
__device__ __forceinline__ void stageB(const int* lut, int4* Bbuf, int rs, int kq,
                                       int4 q0, int4 q1, int sc) {
    int sv = (sc - 112) << 10; sv |= sv << 16;
    int4 o0, o1;
    o0.x = dec2i(lut, q0.x, sv); o0.y = dec2i(lut, q0.y, sv);
    o0.z = dec2i(lut, q0.z, sv); o0.w = dec2i(lut, q0.w, sv);
    o1.x = dec2i(lut, q1.x, sv); o1.y = dec2i(lut, q1.y, sv);
    o1.z = dec2i(lut, q1.z, sv); o1.w = dec2i(lut, q1.w, sv);
    Bbuf[rs * 8 + ((kq * 2) ^ (rs & 7))] = o0;
    Bbuf[rs * 8 + ((kq * 2 + 1) ^ (rs & 7))] = o1;
}

// 2 f32-int4 -> 8 fp16 -> one int4 write into A tile
__device__ __forceinline__ void stageA2(int4* Abuf, int aidx, int4 av0, int4 av1) {
    union { int4 v; float f[4]; } u0, u1; u0.v = av0; u1.v = av1;
    union { _Float16 h[8]; int4 p; } o;
    o.h[0] = (_Float16)u0.f[0]; o.h[1] = (_Float16)u0.f[1];
    o.h[2] = (_Float16)u0.f[2]; o.h[3] = (_Float16)u0.f[3];
    o.h[4] = (_Float16)u1.f[0]; o.h[5] = (_Float16)u1.f[1];
    o.h[6] = (_Float16)u1.f[2]; o.h[7] = (_Float16)u1.f[3];
    Abuf[aidx] = o.p;
}

__global__ void routing_kernel(const float* __restrict__ x, const float* __restrict__ rw,
                               int* __restrict__ top_idx, float* __restrict__ top_w) {
    int t = blockIdx.x;
    int tid = threadIdx.x;          // 256
    int e = tid >> 4, seg = tid & 15;
    const float4* xr = (const float4*)(x + t * HD + seg * 64);
    const float4* wr = (const float4*)(rw + e * HD + seg * 64);
    float p = 0.f;
    #pragma unroll
    for (int i = 0; i < 16; ++i) {
        float4 a = xr[i], b = wr[i];
        p = fmaf(a.x, b.x, fmaf(a.y, b.y, fmaf(a.z, b.z, fmaf(a.w, b.w, p))));
    }
    __shared__ float part[16][16];
    __shared__ float logit[16];
    part[e][seg] = p;
    __syncthreads();
    if (tid < 16) {
        float s = 0.f;
        #pragma unroll
        for (int i = 0; i < 16; ++i) s += part[tid][i];
        logit[tid] = s;
    }
    __syncthreads();
    if (tid == 0) {
        int i0 = 0; float v0 = logit[0];
        #pragma unroll
        for (int i = 1; i < 16; ++i) { if (logit[i] > v0) { v0 = logit[i]; i0 = i; } }
        int i1 = -1; float v1 = -1e30f;
        #pragma unroll
        for (int i = 0; i < 16; ++i) { if (i != i0 && logit[i] > v1) { v1 = logit[i]; i1 = i; } }
        float w0 = 1.f / (1.f + expf(v1 - v0));
        float w1 = 1.f / (1.f + expf(v0 - v1));
        top_idx[t * 2]     = i0;  top_w[t * 2]     = w0;
        top_idx[t * 2 + 1] = i1;  top_w[t * 2 + 1] = w1;
    }
}

__global__ void build_kernel(const int* __restrict__ top_idx,
                             int* __restrict__ cnt, int* __restrict__ pref,
                             int* __restrict__ slot, int* __restrict__ invtok,
                             int* __restrict__ meta, int* __restrict__ tl1) {
    __shared__ int scnt[16], spref[16], scur[16];
    int tid = threadIdx.x;          // 256
    if (tid < 16) scnt[tid] = 0;
    __syncthreads();
    int e = top_idx[tid];
    atomicAdd(&scnt[e], 1);
    __syncthreads();
    if (tid == 0) {
        int s = 0;
        for (int i = 0; i < 16; ++i) { spref[i] = s; pref[i] = s; cnt[i] = scnt[i]; s += scnt[i]; }
        int m1 = 0;
        for (int i = 0; i < 16; ++i) {
            int ntile = (scnt[i] + 31) >> 5;     // 32-token tiles
            for (int m = 0; m < ntile; ++m) tl1[m1++] = (i << 8) | m;
        }
        meta[0] = m1;
    }
    if (tid < 16) scur[tid] = 0;
    __syncthreads();
    int pos = spref[e] + atomicAdd(&scur[e], 1);
    slot[tid] = pos;
    invtok[pos] = tid >> 1;
}

// gu GEMM + SwiGLU: MFMA, BK=64, M=32 tokens (dual acc), dbuf LDS,
// 2-deep register prefetch + raw barriers. exch overlaid on Bsb (dead after K-loop).
__global__ __launch_bounds__(256) void gemm1_mfma(
    const float* __restrict__ x, const int* __restrict__ invtok,
    const int* __restrict__ qblk, const int* __restrict__ qscl,
    const float* __restrict__ bias,
    const int* __restrict__ cnt, const int* __restrict__ pref,
    const int* __restrict__ meta, const int* __restrict__ tl1,
    _Float16* __restrict__ hbuf) {
    __shared__ int lut[256];
    __shared__ int4 Asb[2][256];        // 32 tok x 8 int4 (fp16), dbuf (8 KB)
    __shared__ int4 Bsb[2][512];        // 64 rows x 8 int4, dbuf (16 KB)
    float (*exch)[64][8] = (float (*)[64][8])Bsb;   // 8 KB overlay, used post-loop
    int tid = threadIdx.x;
    lut[tid] = fp4h(tid & 15) | (fp4h(tid >> 4) << 16);
    int wave = tid >> 6, lane = tid & 63;
    int bl = lane & 15, kb4 = lane >> 4;
    int rloc = wave * 16 + bl;
    int rs = tid >> 2, kq = tid & 3;    // B staging: row, k-quarter
    int tokA = tid >> 3, ja = tid & 7;  // A staging: token (0..31), fp16-int4 index
    int aidx = tokA * 8 + (ja ^ (tokA & 7));
    int nwork = meta[0] << 6;

    for (int w = blockIdx.x; w < nwork; w += gridDim.x) {
        int tile = tl1[w >> 6];
        int fc = w & 63;
        int e = tile >> 8, mt = tile & 255;
        int n = cnt[e];
        int nt = n - mt * 32; if (nt > 32) nt = 32;
        int base = pref[e];
        int t0 = base + mt * 32;
        int f0 = fc * 32;

        long rowg = (long)e * 4096 + ((rs < 32) ? (f0 + rs) : (2048 + f0 + rs - 32));
        const int4* wrow = (const int4*)(qblk + rowg * 512);
        const int* srow = qscl + rowg * 32;
        int gtok = invtok[t0 + ((tokA < nt) ? tokA : nt - 1)];
        const int4* arow = (const int4*)x + (long)gtok * 256;   // f32 row = 256 int4

        // step 0 loads
        int4 c0q0 = wrow[kq * 2], c0q1 = wrow[kq * 2 + 1];
        int  c0sc = srow[kq >> 1];
        int4 c0a0 = arow[ja * 2], c0a1 = arow[ja * 2 + 1];
        __syncthreads();                 // lut ready + prev-item LDS retired
        stageA2(Asb[0], aidx, c0a0, c0a1);
        stageB(lut, Bsb[0], rs, kq, c0q0, c0q1, c0sc);
        // prefetch steps 1 (RA), 2 (RB)
        int4 aq0 = wrow[8 + kq * 2], aq1 = wrow[8 + kq * 2 + 1];
        int  asc = srow[2 + (kq >> 1)];
        int4 aa0 = arow[16 + ja * 2], aa1 = arow[16 + ja * 2 + 1];
        int4 bq0 = wrow[16 + kq * 2], bq1 = wrow[16 + kq * 2 + 1];
        int  bsc = srow[4 + (kq >> 1)];
        int4 ba0 = arow[32 + ja * 2], ba1 = arow[32 + ja * 2 + 1];
        BARRIER_LDS();

        f32x4 acc0 = {0.f, 0.f, 0.f, 0.f}, acc1 = {0.f, 0.f, 0.f, 0.f};
        #pragma unroll
        for (int p = 0; p < 8; ++p) {
            int kb = 2 * p;
            #pragma unroll
            for (int ks = 0; ks < 2; ++ks) {
                int g = ks * 4 + kb4;
                XI a0, a1, b;
                b.v = Bsb[0][rloc * 8 + (g ^ (rloc & 7))];
                a0.v = Asb[0][bl * 8 + (g ^ (bl & 7))];
                a1.v = Asb[0][(16 + bl) * 8 + (g ^ (bl & 7))];
                acc0 = __builtin_amdgcn_mfma_f32_16x16x32_f16(a0.h, b.h, acc0, 0, 0, 0);
                acc1 = __builtin_amdgcn_mfma_f32_16x16x32_f16(a1.h, b.h, acc1, 0, 0, 0);
            }
            stageA2(Asb[1], aidx, aa0, aa1);
            stageB(lut, Bsb[1], rs, kq, aq0, aq1, asc);
            if (p < 7) {
                int s = kb + 3;
                aq0 = wrow[s * 8 + kq * 2]; aq1 = wrow[s * 8 + kq * 2 + 1];
                asc = srow[s * 2 + (kq >> 1)];
                aa0 = arow[s * 16 + ja * 2]; aa1 = arow[s * 16 + ja * 2 + 1];
            }
            BARRIER_LDS();
            #pragma unroll
            for (int ks = 0; ks < 2; ++ks) {
                int g = ks * 4 + kb4;
                XI a0, a1, b;
                b.v = Bsb[1][rloc * 8 + (g ^ (rloc & 7))];
                a0.v = Asb[1][bl * 8 + (g ^ (bl & 7))];
                a1.v = Asb[1][(16 + bl) * 8 + (g ^ (bl & 7))];
                acc0 = __builtin_amdgcn_mfma_f32_16x16x32_f16(a0.h, b.h, acc0, 0, 0, 0);
                acc1 = __builtin_amdgcn_mfma_f32_16x16x32_f16(a1.h, b.h, acc1, 0, 0, 0);
            }
            if (p < 7) {
                stageA2(Asb[0], aidx, ba0, ba1);
                stageB(lut, Bsb[0], rs, kq, bq0, bq1, bsc);
                if (p < 6) {
                    int s = kb + 4;
                    bq0 = wrow[s * 8 + kq * 2]; bq1 = wrow[s * 8 + kq * 2 + 1];
                    bsc = srow[s * 2 + (kq >> 1)];
                    ba0 = arow[s * 16 + ja * 2]; ba1 = arow[s * 16 + ja * 2 + 1];
                }
            }
            BARRIER_LDS();
        }
        // Bsb dead from here (last barrier passed): overlay exch
        #pragma unroll
        for (int i = 0; i < 4; ++i) {
            exch[wave][lane][i] = acc0[i];
            exch[wave][lane][4 + i] = acc1[i];
        }
        __syncthreads();
        // epilogue: 32 tok x 32 f; thread: fl = tid&31, tokens (tid>>5)+d*8, d=0..3
        int fl = tid & 31, wv = fl >> 4, col = fl & 15;
        float bg = bias[(long)e * 4096 + f0 + fl];
        float bu = bias[(long)e * 4096 + 2048 + f0 + fl];
        #pragma unroll
        for (int d = 0; d < 4; ++d) {
            int tk = (tid >> 5) + d * 8;     // 0..31
            int tr = tk & 15;
            int ln = ((tr >> 2) << 4) | col;
            int rg = (tr & 3) + ((tk >= 16) ? 4 : 0);
            float g = exch[wv][ln][rg] + bg;
            float u = exch[wv + 2][ln][rg] + bu;
            float h = (g / (1.f + expf(-g))) * u;
            if (tk < nt)
                hbuf[(long)(t0 + tk) * FD + f0 + fl] = (_Float16)(h * 0.0625f);  // 2^-4
        }
        __syncthreads();   // protect LDS before next item's prologue
    }
}

// down GEMM: MFMA, BK=64, M=32 tokens (dual acc), dbuf LDS, 2-deep prefetch +
// raw barriers; K split in 2 halves -> y0/y1 (no atomics).
__global__ __launch_bounds__(256) void gemm2_mfma(
    const _Float16* __restrict__ hbuf, const int* __restrict__ qblk,
    const int* __restrict__ qscl, const float* __restrict__ bias,
    const int* __restrict__ cnt, const int* __restrict__ pref,
    const int* __restrict__ meta, const int* __restrict__ tl1,
    float* __restrict__ y0p, float* __restrict__ y1p) {
    __shared__ int lut[256];
    __shared__ int4 Asb[2][256];        // 32 tok x 8 int4 (8 KB)
    __shared__ int4 Bsb[2][512];
    int tid = threadIdx.x;
    lut[tid] = fp4h(tid & 15) | (fp4h(tid >> 4) << 16);
    int wave = tid >> 6, lane = tid & 63;
    int bl = lane & 15, kb4 = lane >> 4;
    int rloc = wave * 16 + bl;
    int rs = tid >> 2, kq = tid & 3;
    int tokA = tid >> 3, ga = tid & 7;
    int aidx = tokA * 8 + (ga ^ (tokA & 7));
    int nwork = meta[0] << 5;           // 16 h-chunks x 2 k-halves

    for (int w = blockIdx.x; w < nwork; w += gridDim.x) {
        int tile = tl1[w >> 5];
        int sub = w & 31;
        int hc = sub & 15, kh = sub >> 4;
        int e = tile >> 8, mt = tile & 255;
        int n = cnt[e];
        int nt = n - mt * 32; if (nt > 32) nt = 32;
        int base = pref[e];
        int t0 = base + mt * 32;
        int h0 = hc * 64;

        long rowg = (long)e * HD + h0 + rs;
        const int4* wrow = (const int4*)(qblk + rowg * 1024) + (kh * 16) * 8;
        const int* srow = qscl + rowg * 64 + kh * 32;
        int tclamp = (tokA < nt) ? tokA : nt - 1;
        const int4* arow = (const int4*)hbuf + (long)(t0 + tclamp) * 256 + kh * 128;

        int4 c0q0 = wrow[kq * 2], c0q1 = wrow[kq * 2 + 1];
        int  c0sc = srow[kq >> 1];
        int4 c0av = arow[ga];
        __syncthreads();
        Asb[0][aidx] = c0av;
        stageB(lut, Bsb[0], rs, kq, c0q0, c0q1, c0sc);
        int4 aq0 = wrow[8 + kq * 2], aq1 = wrow[8 + kq * 2 + 1];
        int  asc = srow[2 + (kq >> 1)];
        int4 aav = arow[8 + ga];
        int4 bq0 = wrow[16 + kq * 2], bq1 = wrow[16 + kq * 2 + 1];
        int  bsc = srow[4 + (kq >> 1)];
        int4 bav = arow[16 + ga];
        BARRIER_LDS();

        f32x4 acc0 = {0.f, 0.f, 0.f, 0.f}, acc1 = {0.f, 0.f, 0.f, 0.f};
        #pragma unroll
        for (int p = 0; p < 8; ++p) {
            int kb = 2 * p;
            #pragma unroll
            for (int ks = 0; ks < 2; ++ks) {
                int g = ks * 4 + kb4;
                XI a0, a1, b;
                b.v = Bsb[0][rloc * 8 + (g ^ (rloc & 7))];
                a0.v = Asb[0][bl * 8 + (g ^ (bl & 7))];
                a1.v = Asb[0][(16 + bl) * 8 + (g ^ (bl & 7))];
                acc0 = __builtin_amdgcn_mfma_f32_16x16x32_f16(a0.h, b.h, acc0, 0, 0, 0);
                acc1 = __builtin_amdgcn_mfma_f32_16x16x32_f16(a1.h, b.h, acc1, 0, 0, 0);
            }
            Asb[1][aidx] = aav;
            stageB(lut, Bsb[1], rs, kq, aq0, aq1, asc);
            if (p < 7) {
                int s = kb + 3;
                aq0 = wrow[s * 8 + kq * 2]; aq1 = wrow[s * 8 + kq * 2 + 1];
                asc = srow[s * 2 + (kq >> 1)];
                aav = arow[s * 8 + ga];
            }
            BARRIER_LDS();
            #pragma unroll
            for (int ks = 0; ks < 2; ++ks) {
                int g = ks * 4 + kb4;
                XI a0, a1, b;
                b.v = Bsb[1][rloc * 8 + (g ^ (rloc & 7))];
                a0.v = Asb[1][bl * 8 + (g ^ (bl & 7))];
                a1.v = Asb[1][(16 + bl) * 8 + (g ^ (bl & 7))];
                acc0 = __builtin_amdgcn_mfma_f32_16x16x32_f16(a0.h, b.h, acc0, 0, 0, 0);
                acc1 = __builtin_amdgcn_mfma_f32_16x16x32_f16(a1.h, b.h, acc1, 0, 0, 0);
            }
            if (p < 7) {
                Asb[0][aidx] = bav;
                stageB(lut, Bsb[0], rs, kq, bq0, bq1, bsc);
                if (p < 6) {
                    int s = kb + 4;
                    bq0 = wrow[s * 8 + kq * 2]; bq1 = wrow[s * 8 + kq * 2 + 1];
                    bsc = srow[s * 2 + (kq >> 1)];
                    bav = arow[s * 8 + ga];
                }
            }
            BARRIER_LDS();
        }
        // C: col=lane&15 -> h row; token rows: acc0 -> kb4*4+r, acc1 -> 16+kb4*4+r
        int hcol = h0 + wave * 16 + bl;
        float bv = (kh == 0) ? bias[(long)e * HD + hcol] : 0.f;
        float* yp = (kh == 0) ? y0p : y1p;
        #pragma unroll
        for (int r = 0; r < 4; ++r) {
            int row0 = kb4 * 4 + r;
            if (row0 < nt)
                yp[(long)(t0 + row0) * HD + hcol] = acc0[r] * 16.f + bv;
            int row1 = 16 + kb4 * 4 + r;
            if (row1 < nt)
                yp[(long)(t0 + row1) * HD + hcol] = acc1[r] * 16.f + bv;
        }
        __syncthreads();   // protect LDS before next item's prologue writes
    }
}

__global__ void combine_kernel(const float* __restrict__ y0, const float* __restrict__ y1,
                               const int* __restrict__ slot, const float* __restrict__ topw,
                               float* __restrict__ out) {
    int t = blockIdx.x;
    int i = threadIdx.x;   // 256, float4 each
    int s0 = slot[2 * t], s1 = slot[2 * t + 1];
    float w0 = topw[2 * t], w1 = topw[2 * t + 1];
    float4 a0 = ((const float4*)(y0 + (long)s0 * HD))[i];
    float4 a1 = ((const float4*)(y1 + (long)s0 * HD))[i];
    float4 b0 = ((const float4*)(y0 + (long)s1 * HD))[i];
    float4 b1 = ((const float4*)(y1 + (long)s1 * HD))[i];
    float4 o;
    o.x = w0 * (a0.x + a1.x) + w1 * (b0.x + b1.x);
    o.y = w0 * (a0.y + a1.y) + w1 * (b0.y + b1.y);
    o.z = w0 * (a0.z + a1.z) + w1 * (b0.z + b1.z);
    o.w = w0 * (a0.w + a1.w) + w1 * (b0.w + b1.w);
    ((float4*)(out + (long)t * HD))[i] = o;
}

extern "C" void kernel_launch(void* const* d_in, const int* in_sizes, int n_in,
                              void* d_out, int out_size, void* d_ws, size_t ws_size,
                              hipStream_t stream) {
    const float* x          = (const float*)d_in[0];
    const float* rw         = (const float*)d_in[1];
    const float* bias_gu    = (const float*)d_in[2];
    const float* bias_down  = (const float*)d_in[3];
    const int*   blocks_gu  = (const int*)d_in[4];
    const int*   scales_gu  = (const int*)d_in[5];
    const int*   blocks_down= (const int*)d_in[6];
    const int*   scales_down= (const int*)d_in[7];
    float* out = (float*)d_out;
    int*   wsI = (int*)d_ws;
    float* wsF = (float*)d_ws;
    _Float16* hbuf = (_Float16*)(wsI + HBUF_OFF);
    float*    y0   = wsF + Y0_OFF;
    float*    y1   = wsF + Y1_OFF;

    routing_kernel<<<128, 256, 0, stream>>>(x, rw, wsI + TOPI_OFF, wsF + TOPW_OFF);
    build_kernel<<<1, 256, 0, stream>>>(wsI + TOPI_OFF, wsI + CNT_OFF, wsI + PREF_OFF,
                                        wsI + SLOT_OFF, wsI + INVT_OFF,
                                        wsI + META_OFF, wsI + TL1_OFF);
    gemm1_mfma<<<2048, 256, 0, stream>>>(x, wsI + INVT_OFF, blocks_gu, scales_gu, bias_gu,
                                         wsI + CNT_OFF, wsI + PREF_OFF,
                                         wsI + META_OFF, wsI + TL1_OFF, hbuf);
    gemm2_mfma<<<1024, 256, 0, stream>>>(hbuf, blocks_down, scales_down, bias_down,
                                         wsI + CNT_OFF, wsI + PREF_OFF,
                                         wsI + META_OFF, wsI + TL1_OFF, y0, y1);
    combine_kernel<<<128, 256, 0, stream>>>(y0, y1, wsI + SLOT_OFF, wsF + TOPW_OFF, out);
}